// Round 3
// baseline (369.450 us; speedup 1.0000x reference)
//
#include <hip/hip_runtime.h>
#include <math.h>

// LatentGraphNetwork: out = LN(GELU(x @ W_eff + b_eff) @ W_out + b_out)
//   W_eff = W_upd[:128] + (W_msg@graph)@W_upd[128:]   (precomputed per launch)
//   b_eff = b_upd + (b_msg@graph)@W_upd[128:]
// B=64, T=4096, D=128 -> 262144 rows of 128 fp32.
//
// R3 note: the __syncthreads() after the GELU->LDS write is REQUIRED even
// though Hs is wave-private — removing it passed first-call but corrupted
// graph-replay outputs (R2 post-timing absmax 5.27). Do not remove again.

#define D 128
#define NROWS (64 * 4096)

typedef __bf16 bf16x8 __attribute__((ext_vector_type(8)));
typedef float  f32x4  __attribute__((ext_vector_type(4)));

// ---------------- prelude 1: G2 = W_msg@graph, b2tmp = b_msg@graph, W2t = W_out^T (bf16)
// 16 blocks x 256 threads; graph staged in LDS (64 KB), coalesced.
__global__ __launch_bounds__(256) void prep1(
    const float* __restrict__ W_msg, const float* __restrict__ graph,
    const float* __restrict__ b_msg, const float* __restrict__ W_out,
    float* __restrict__ G2, float* __restrict__ b2tmp, __bf16* __restrict__ W2t) {
    __shared__ float gs[D * D];  // 64 KB
    const int tid = threadIdx.x;
    {
        const float4* g4 = (const float4*)graph;
        float4* s4 = (float4*)gs;
#pragma unroll
        for (int it = 0; it < (D * D / 4) / 256; ++it)
            s4[tid + it * 256] = g4[tid + it * 256];
    }
    __syncthreads();
    const int i0 = blockIdx.x * 8;
#pragma unroll
    for (int p = 0; p < 4; ++p) {
        const int flat = tid + p * 256;
        const int i = i0 + (flat >> 7);
        const int g = flat & 127;
        const float* wrow = W_msg + i * D;  // broadcast across the 128 threads sharing i
        float s = 0.f;
#pragma unroll 8
        for (int h = 0; h < D; ++h) s += wrow[h] * gs[h * D + g];
        G2[i * D + g] = s;
        W2t[g * D + i] = (__bf16)W_out[i * D + g];
    }
    if (blockIdx.x == 0 && tid < 128) {
        float sb = 0.f;
#pragma unroll 8
        for (int h = 0; h < D; ++h) sb += b_msg[h] * gs[h * D + tid];
        b2tmp[tid] = sb;
    }
}

// ---------------- prelude 2: W1t = W_eff^T (bf16), b_eff
// 16 blocks x 256 threads; W_upd lower half staged in LDS (64 KB).
__global__ __launch_bounds__(256) void prep2(
    const float* __restrict__ W_upd, const float* __restrict__ b_upd,
    const float* __restrict__ G2, const float* __restrict__ b2tmp,
    __bf16* __restrict__ W1t, float* __restrict__ b_eff) {
    __shared__ float wls[D * D];  // W_upd rows 128..255, 64 KB
    const int tid = threadIdx.x;
    {
        const float4* w4 = (const float4*)(W_upd + D * D);
        float4* s4 = (float4*)wls;
#pragma unroll
        for (int it = 0; it < (D * D / 4) / 256; ++it)
            s4[tid + it * 256] = w4[tid + it * 256];
    }
    __syncthreads();
    const int i0 = blockIdx.x * 8;
#pragma unroll
    for (int p = 0; p < 4; ++p) {
        const int flat = tid + p * 256;
        const int i = i0 + (flat >> 7);
        const int o = flat & 127;
        const float* g2row = G2 + i * D;  // broadcast
        float s = W_upd[i * D + o];
#pragma unroll 8
        for (int g = 0; g < D; ++g) s += g2row[g] * wls[g * D + o];
        W1t[o * D + i] = (__bf16)s;
    }
    if (blockIdx.x == 0 && tid < 128) {
        float sb = b_upd[tid];
#pragma unroll 8
        for (int g = 0; g < D; ++g) sb += b2tmp[g] * wls[g * D + tid];
        b_eff[tid] = sb;
    }
}

// fast GELU: v * sigmoid(2*sqrt(2/pi)*(v + 0.044715 v^3)); max abs err ~1e-3
__device__ __forceinline__ float gelu_fast(float v) {
    const float u = 1.5957691216057308f * v * (1.0f + 0.044715f * v * v);
    return v / (1.0f + __expf(-u));
}

// ---------------- fused main: per wave, 16 rows end-to-end
__global__ __launch_bounds__(256) void fused_main(
    const float* __restrict__ x, const __bf16* __restrict__ W1t,
    const float* __restrict__ b1, const __bf16* __restrict__ W2t,
    const float* __restrict__ b2, const float* __restrict__ gamma,
    const float* __restrict__ beta, float* __restrict__ out) {

    __shared__ __align__(16) __bf16 Hs[4][16][136];  // per-wave private, +8 pad

    const int tid = threadIdx.x;
    const int w = tid >> 6;        // wave 0..3
    const int l = tid & 63;        // lane
    const int q = l >> 4;          // quad-of-16
    const int m = l & 15;          // within-16
    const int rowbase = blockIdx.x * 64 + w * 16;

    // per-lane column constants for the 8 16-col tiles
    float b1v[8], b2v[8], gv[8], bv[8];
#pragma unroll
    for (int t = 0; t < 8; ++t) {
        const int c = t * 16 + m;
        b1v[t] = b1[c]; b2v[t] = b2[c]; gv[t] = gamma[c]; bv[t] = beta[c];
    }

    // ---- GEMM1: H = GELU(x @ W_eff + b_eff), x fp32 -> bf16 on the fly
    f32x4 acc[8];
#pragma unroll
    for (int t = 0; t < 8; ++t) acc[t] = (f32x4)(0.0f);

    const float* xrow = x + (size_t)(rowbase + m) * D;
#pragma unroll
    for (int ks = 0; ks < 4; ++ks) {
        const float4* xp = (const float4*)(xrow + ks * 32 + q * 8);
        const float4 xa = xp[0];
        const float4 xb = xp[1];
        bf16x8 a;
        a[0] = (__bf16)xa.x; a[1] = (__bf16)xa.y; a[2] = (__bf16)xa.z; a[3] = (__bf16)xa.w;
        a[4] = (__bf16)xb.x; a[5] = (__bf16)xb.y; a[6] = (__bf16)xb.z; a[7] = (__bf16)xb.w;
#pragma unroll
        for (int t = 0; t < 8; ++t) {
            const bf16x8 bfr = *(const bf16x8*)(W1t + (t * 16 + m) * D + ks * 32 + q * 8);
            acc[t] = __builtin_amdgcn_mfma_f32_16x16x32_bf16(a, bfr, acc[t], 0, 0, 0);
        }
    }

    // bias + fast GELU, write bf16 to wave-private LDS (C-layout -> row-major)
#pragma unroll
    for (int t = 0; t < 8; ++t) {
#pragma unroll
        for (int j = 0; j < 4; ++j) {
            const float v = acc[t][j] + b1v[t];
            Hs[w][q * 4 + j][t * 16 + m] = (__bf16)gelu_fast(v);
        }
    }
    __syncthreads();  // REQUIRED (see R3 note at top) — do not remove

    // ---- GEMM2: O = H @ W_out
    f32x4 acc2[8];
#pragma unroll
    for (int t = 0; t < 8; ++t) acc2[t] = (f32x4)(0.0f);
#pragma unroll
    for (int ks = 0; ks < 4; ++ks) {
        const bf16x8 a = *(const bf16x8*)&Hs[w][m][ks * 32 + q * 8];
#pragma unroll
        for (int t = 0; t < 8; ++t) {
            const bf16x8 bfr = *(const bf16x8*)(W2t + (t * 16 + m) * D + ks * 32 + q * 8);
            acc2[t] = __builtin_amdgcn_mfma_f32_16x16x32_bf16(a, bfr, acc2[t], 0, 0, 0);
        }
    }

    // ---- bias + LayerNorm over 128 cols (rows live in 16-lane groups)
    float vsum[4] = {0.f, 0.f, 0.f, 0.f}, vsq[4] = {0.f, 0.f, 0.f, 0.f};
#pragma unroll
    for (int t = 0; t < 8; ++t) {
#pragma unroll
        for (int j = 0; j < 4; ++j) {
            const float v = acc2[t][j] + b2v[t];
            acc2[t][j] = v;
            vsum[j] += v;
            vsq[j] += v * v;
        }
    }
#pragma unroll
    for (int j = 0; j < 4; ++j) {
#pragma unroll
        for (int mask = 1; mask <= 8; mask <<= 1) {
            vsum[j] += __shfl_xor(vsum[j], mask);
            vsq[j]  += __shfl_xor(vsq[j], mask);
        }
    }
    float mu[4], rstd[4];
#pragma unroll
    for (int j = 0; j < 4; ++j) {
        mu[j] = vsum[j] * (1.0f / 128.0f);
        const float var = vsq[j] * (1.0f / 128.0f) - mu[j] * mu[j];
        rstd[j] = rsqrtf(var + 1e-5f);
    }
#pragma unroll
    for (int t = 0; t < 8; ++t) {
#pragma unroll
        for (int j = 0; j < 4; ++j) {
            const float o = (acc2[t][j] - mu[j]) * rstd[j] * gv[t] + bv[t];
            out[(size_t)(rowbase + q * 4 + j) * D + t * 16 + m] = o;
        }
    }
}

extern "C" void kernel_launch(void* const* d_in, const int* in_sizes, int n_in,
                              void* d_out, int out_size, void* d_ws, size_t ws_size,
                              hipStream_t stream) {
    const float* x     = (const float*)d_in[0];
    const float* graph = (const float*)d_in[1];
    const float* W_msg = (const float*)d_in[2];
    const float* b_msg = (const float*)d_in[3];
    const float* W_upd = (const float*)d_in[4];
    const float* b_upd = (const float*)d_in[5];
    const float* W_out = (const float*)d_in[6];
    const float* b_out = (const float*)d_in[7];
    const float* gamma = (const float*)d_in[8];
    const float* beta  = (const float*)d_in[9];
    float* out = (float*)d_out;

    char* ws = (char*)d_ws;
    float*  G2    = (float*)(ws + 0);        // 128*128 fp32 = 65536 B
    float*  b2tmp = (float*)(ws + 65536);    // 128 fp32
    float*  b_eff = (float*)(ws + 66048);    // 128 fp32
    __bf16* W1t   = (__bf16*)(ws + 66560);   // 128*128 bf16 = 32768 B
    __bf16* W2t   = (__bf16*)(ws + 99328);   // 128*128 bf16 = 32768 B

    prep1<<<16, 256, 0, stream>>>(W_msg, graph, b_msg, W_out, G2, b2tmp, W2t);
    prep2<<<16, 256, 0, stream>>>(W_upd, b_upd, G2, b2tmp, W1t, b_eff);
    fused_main<<<NROWS / 64, 256, 0, stream>>>(x, W1t, b_eff, W2t, b_out, gamma, beta, out);
}

// Round 4
// 289.288 us; speedup vs baseline: 1.2771x; 1.2771x over previous
//
#include <hip/hip_runtime.h>
#include <math.h>

// LatentGraphNetwork: out = LN(GELU(x @ W_eff + b_eff) @ W_out + b_out)
//   W_eff = W_upd[:128] + (W_msg@graph)@W_upd[128:]   (precomputed per launch)
//   b_eff = b_upd + (b_msg@graph)@W_upd[128:]
// B=64, T=4096, D=128 -> 262144 rows of 128 fp32.
//
// Correctness note (R2/R3): a __syncthreads() between the GELU->LDS transform
// write and its read is REQUIRED (compiler may reorder the may-alias ds ops).
// R4 uses two barriers per tile to fence both directions.

#define D 128
#define NROWS (64 * 4096)

typedef __bf16 bf16x8 __attribute__((ext_vector_type(8)));
typedef float  f32x4  __attribute__((ext_vector_type(4)));

// swizzled element index for a 128x128 bf16 matrix stored for conflict-free
// ds_read_b128 B-fragments: element (o, i) -> o*128 + (((i>>3) ^ (o&15))<<3) + (i&7)
__device__ __forceinline__ int wswz(int o, int i) {
    return o * 128 + ((((i >> 3) ^ (o & 15)) & 15) << 3) + (i & 7);
}

// ---------------- prelude 1: G2 = W_msg@graph, b2tmp = b_msg@graph, W2s = swizzled W_out^T (bf16)
__global__ __launch_bounds__(256) void prep1(
    const float* __restrict__ W_msg, const float* __restrict__ graph,
    const float* __restrict__ b_msg, const float* __restrict__ W_out,
    float* __restrict__ G2, float* __restrict__ b2tmp, __bf16* __restrict__ W2s) {
    __shared__ float gs[D * D];  // 64 KB
    const int tid = threadIdx.x;
    {
        const float4* g4 = (const float4*)graph;
        float4* s4 = (float4*)gs;
#pragma unroll
        for (int it = 0; it < (D * D / 4) / 256; ++it)
            s4[tid + it * 256] = g4[tid + it * 256];
    }
    __syncthreads();
    const int i0 = blockIdx.x * 8;
#pragma unroll
    for (int p = 0; p < 4; ++p) {
        const int flat = tid + p * 256;
        const int i = i0 + (flat >> 7);   // row of W_out / W_msg
        const int g = flat & 127;         // col
        const float* wrow = W_msg + i * D;
        float s = 0.f;
#pragma unroll 8
        for (int h = 0; h < D; ++h) s += wrow[h] * gs[h * D + g];
        G2[i * D + g] = s;
        // W2t element (o=g, k=i), swizzled
        W2s[wswz(g, i)] = (__bf16)W_out[i * D + g];
    }
    if (blockIdx.x == 0 && tid < 128) {
        float sb = 0.f;
#pragma unroll 8
        for (int h = 0; h < D; ++h) sb += b_msg[h] * gs[h * D + tid];
        b2tmp[tid] = sb;
    }
}

// ---------------- prelude 2: W1s = swizzled W_eff^T (bf16), b_eff
__global__ __launch_bounds__(256) void prep2(
    const float* __restrict__ W_upd, const float* __restrict__ b_upd,
    const float* __restrict__ G2, const float* __restrict__ b2tmp,
    __bf16* __restrict__ W1s, float* __restrict__ b_eff) {
    __shared__ float wls[D * D];  // W_upd rows 128..255
    const int tid = threadIdx.x;
    {
        const float4* w4 = (const float4*)(W_upd + D * D);
        float4* s4 = (float4*)wls;
#pragma unroll
        for (int it = 0; it < (D * D / 4) / 256; ++it)
            s4[tid + it * 256] = w4[tid + it * 256];
    }
    __syncthreads();
    const int i0 = blockIdx.x * 8;
#pragma unroll
    for (int p = 0; p < 4; ++p) {
        const int flat = tid + p * 256;
        const int i = i0 + (flat >> 7);   // input dim
        const int o = flat & 127;         // output dim
        const float* g2row = G2 + i * D;
        float s = W_upd[i * D + o];
#pragma unroll 8
        for (int g = 0; g < D; ++g) s += g2row[g] * wls[g * D + o];
        W1s[wswz(o, i)] = (__bf16)s;
    }
    if (blockIdx.x == 0 && tid < 128) {
        float sb = b_upd[tid];
#pragma unroll 8
        for (int g = 0; g < D; ++g) sb += b2tmp[g] * wls[g * D + tid];
        b_eff[tid] = sb;
    }
}

// fast GELU: v * sigmoid(2*sqrt(2/pi)*(v + 0.044715 v^3)); max abs err ~1e-3
__device__ __forceinline__ float gelu_fast(float v) {
    const float u = 1.5957691216057308f * v * (1.0f + 0.044715f * v * v);
    return v / (1.0f + __expf(-u));
}

// ---------------- fused main: weights in LDS, 4 tiles (64 rows) per wave
__global__ __launch_bounds__(256) void fused_main(
    const float* __restrict__ x, const __bf16* __restrict__ Wsrc,  // [W1s|W2s] 64KB
    const float* __restrict__ b1, const float* __restrict__ b2,
    const float* __restrict__ gamma, const float* __restrict__ beta,
    float* __restrict__ out) {

    __shared__ __align__(16) __bf16 Wlds[2 * 128 * 128];  // 64 KB: W1 @0, W2 @16384
    __shared__ __align__(16) __bf16 tf[4][16 * 128];      // 16 KB transform, swizzled

    const int tid = threadIdx.x;
    // ---- stage weights (contiguous 64 KB copy; source pre-swizzled by preludes)
    {
        const float4* src4 = (const float4*)Wsrc;
        float4* dst4 = (float4*)Wlds;
#pragma unroll
        for (int it = 0; it < 16; ++it) dst4[it * 256 + tid] = src4[it * 256 + tid];
    }

    const int w = tid >> 6;        // wave 0..3
    const int l = tid & 63;
    const int q = l >> 4;          // quad-of-16
    const int m = l & 15;
    __bf16* tfw = &tf[w][0];       // wave-private 4 KB slice

    // per-lane column constants
    float b1v[8], b2v[8], gv[8], bv[8];
#pragma unroll
    for (int t = 0; t < 8; ++t) {
        const int c = t * 16 + m;
        b1v[t] = b1[c]; b2v[t] = b2[c]; gv[t] = gamma[c]; bv[t] = beta[c];
    }

    __syncthreads();  // weights staged

    const int rowbase0 = blockIdx.x * 256 + w * 64;

    // preload x for tile 0
    float4 xr[8];
    {
        const float* xrow = x + (size_t)(rowbase0 + m) * D;
#pragma unroll
        for (int ks = 0; ks < 4; ++ks) {
            const float4* xp = (const float4*)(xrow + ks * 32 + q * 8);
            xr[2 * ks]     = xp[0];
            xr[2 * ks + 1] = xp[1];
        }
    }

    for (int tile = 0; tile < 4; ++tile) {
        const int rowbase = rowbase0 + tile * 16;

        // ---- prefetch next tile's x (issued early; covered by GEMM1+GELU)
        float4 xn[8];
        if (tile < 3) {
            const float* xnrow = x + (size_t)(rowbase + 16 + m) * D;
#pragma unroll
            for (int ks = 0; ks < 4; ++ks) {
                const float4* xp = (const float4*)(xnrow + ks * 32 + q * 8);
                xn[2 * ks]     = xp[0];
                xn[2 * ks + 1] = xp[1];
            }
        }

        // ---- convert current x to bf16 A-frags
        bf16x8 a[4];
#pragma unroll
        for (int ks = 0; ks < 4; ++ks) {
            const float4 xa = xr[2 * ks], xb = xr[2 * ks + 1];
            a[ks][0] = (__bf16)xa.x; a[ks][1] = (__bf16)xa.y;
            a[ks][2] = (__bf16)xa.z; a[ks][3] = (__bf16)xa.w;
            a[ks][4] = (__bf16)xb.x; a[ks][5] = (__bf16)xb.y;
            a[ks][6] = (__bf16)xb.z; a[ks][7] = (__bf16)xb.w;
        }

        // ---- GEMM1: H = x @ W_eff  (B-frags from LDS, swizzled)
        f32x4 acc[8];
#pragma unroll
        for (int t = 0; t < 8; ++t) acc[t] = (f32x4)(0.0f);
#pragma unroll
        for (int ks = 0; ks < 4; ++ks) {
            const int blk = (((ks * 4 + q) ^ m) & 15) << 3;
#pragma unroll
            for (int t = 0; t < 8; ++t) {
                const bf16x8 bfr = *(const bf16x8*)&Wlds[(t * 16 + m) * 128 + blk];
                acc[t] = __builtin_amdgcn_mfma_f32_16x16x32_bf16(a[ks], bfr, acc[t], 0, 0, 0);
            }
        }

        // ---- bias + GELU -> swizzled wave-private transform buffer
#pragma unroll
        for (int t = 0; t < 8; ++t) {
#pragma unroll
            for (int j = 0; j < 4; ++j) {
                const float v = acc[t][j] + b1v[t];
                const int r = q * 4 + j;
                const int blk = (((t * 2 + (m >> 3)) ^ r) & 15) << 3;
                tfw[r * 128 + blk + (m & 7)] = (__bf16)gelu_fast(v);
            }
        }
        __syncthreads();  // REQUIRED: fence write->read (R2 lesson)

        // ---- GEMM2: O = H @ W_out
        f32x4 acc2[8];
#pragma unroll
        for (int t = 0; t < 8; ++t) acc2[t] = (f32x4)(0.0f);
#pragma unroll
        for (int ks = 0; ks < 4; ++ks) {
            const int blk = (((ks * 4 + q) ^ m) & 15) << 3;
            const bf16x8 af = *(const bf16x8*)&tfw[m * 128 + blk];
#pragma unroll
            for (int t = 0; t < 8; ++t) {
                const bf16x8 bfr = *(const bf16x8*)&Wlds[16384 + (t * 16 + m) * 128 + blk];
                acc2[t] = __builtin_amdgcn_mfma_f32_16x16x32_bf16(af, bfr, acc2[t], 0, 0, 0);
            }
        }
        __syncthreads();  // fence read(i) -> write(i+1)

        // ---- bias + LayerNorm + store
        float vsum[4] = {0.f, 0.f, 0.f, 0.f}, vsq[4] = {0.f, 0.f, 0.f, 0.f};
#pragma unroll
        for (int t = 0; t < 8; ++t) {
#pragma unroll
            for (int j = 0; j < 4; ++j) {
                const float v = acc2[t][j] + b2v[t];
                acc2[t][j] = v;
                vsum[j] += v;
                vsq[j] += v * v;
            }
        }
#pragma unroll
        for (int j = 0; j < 4; ++j) {
#pragma unroll
            for (int mask = 1; mask <= 8; mask <<= 1) {
                vsum[j] += __shfl_xor(vsum[j], mask);
                vsq[j]  += __shfl_xor(vsq[j], mask);
            }
        }
#pragma unroll
        for (int j = 0; j < 4; ++j) {
            const float mu = vsum[j] * (1.0f / 128.0f);
            const float var = vsq[j] * (1.0f / 128.0f) - mu * mu;
            const float rstd = rsqrtf(var + 1e-5f);
            float* orow = out + (size_t)(rowbase + q * 4 + j) * D;
#pragma unroll
            for (int t = 0; t < 8; ++t)
                orow[t * 16 + m] = (acc2[t][j] - mu) * rstd * gv[t] + bv[t];
        }

        // rotate prefetch
        if (tile < 3) {
#pragma unroll
            for (int k = 0; k < 8; ++k) xr[k] = xn[k];
        }
    }
}

extern "C" void kernel_launch(void* const* d_in, const int* in_sizes, int n_in,
                              void* d_out, int out_size, void* d_ws, size_t ws_size,
                              hipStream_t stream) {
    const float* x     = (const float*)d_in[0];
    const float* graph = (const float*)d_in[1];
    const float* W_msg = (const float*)d_in[2];
    const float* b_msg = (const float*)d_in[3];
    const float* W_upd = (const float*)d_in[4];
    const float* b_upd = (const float*)d_in[5];
    const float* W_out = (const float*)d_in[6];
    const float* b_out = (const float*)d_in[7];
    const float* gamma = (const float*)d_in[8];
    const float* beta  = (const float*)d_in[9];
    float* out = (float*)d_out;

    char* ws = (char*)d_ws;
    __bf16* W1s   = (__bf16*)(ws + 0);       // 32768 B (swizzled bf16 W_eff^T)
    __bf16* W2s   = (__bf16*)(ws + 32768);   // 32768 B (swizzled bf16 W_out^T)
    float*  G2    = (float*)(ws + 65536);    // 65536 B
    float*  b2tmp = (float*)(ws + 131072);   // 512 B
    float*  b_eff = (float*)(ws + 131584);   // 512 B

    prep1<<<16, 256, 0, stream>>>(W_msg, graph, b_msg, W_out, G2, b2tmp, W2s);
    prep2<<<16, 256, 0, stream>>>(W_upd, b_upd, G2, b2tmp, W1s, b_eff);
    fused_main<<<NROWS / 256, 256, 0, stream>>>(x, W1s, b_eff, b_out, gamma, beta, out);
}